// Round 17
// baseline (162.218 us; speedup 1.0000x reference)
//
#include <hip/hip_runtime.h>

// LSTM fused forward: B=131072, T=48, I=5, H=8, classes=2.
// Round-17: OCCUPANCY experiment — 16x16x32 formulation (EPW=16 -> 8192
// waves = 8/SIMD, double r16's 4) with every verified improvement:
//  - r5-verified A/bias/C maps: A0=[i,f interleaved rows], A1=[g,o], k0-15 =
//    W_hi (x cols 0-4, h cols 8-15), k16-31 = W_lo. pass1 B=[B_hi|B_hi],
//    pass2 B=[B_lo|B_lo] => full (W_hi+W_lo)x(B_hi+B_lo) in 2 MFMAs.
//  - x single-bf16 (r10): B_lo x-slots are zero (s_zero broadcast); W_lo*h_lo
//    KEPT (better than r10's 32x32 which dropped it).
//  - LDS-h transport, merged divergent pointers (r16-verified): grp0,2 -> x
//    rows; grp1,3 -> h rows. Wave-private, in-order DS => barrier-free.
//  - packed-f32 unitstep/FC via float2 ext-vectors (r15-verified).
//  - CH=8 staging, single x buffer.
// __launch_bounds__(128, 8) caps VGPR at 64 (r5 fit 64 naturally).

#define T 48
#define CH 8
#define NCH (T / CH)
#define EPW 16              // elems per wave
#define WPB 2
#define EPB (EPW * WPB)     // 32
#define THREADS (64 * WPB)
#define WAVE_LDS 2560       // 2048 x (8 rows x 16 elems x 16B) | 256 h_hi | 256 h_lo

typedef __attribute__((ext_vector_type(8))) short    short8v;
typedef __attribute__((ext_vector_type(2))) float    f32x2;
typedef __attribute__((ext_vector_type(4))) float    f32x4;
typedef __attribute__((ext_vector_type(4))) unsigned u32x4;

#if __has_builtin(__builtin_amdgcn_exp2f)
#define EXP2F(x) __builtin_amdgcn_exp2f(x)
#else
#define EXP2F(x) exp2f(x)
#endif
#if __has_builtin(__builtin_amdgcn_rcpf)
#define RCPF(x) __builtin_amdgcn_rcpf(x)
#else
#define RCPF(x) (1.0f / (x))
#endif

#define SCL_SIG  (-1.44269504f)   // sigmoid gates: e = 2^(scl*v)
#define SCL_TANH (-2.88539008f)   // tanh gates:    q = 2^(scl*v)

__device__ __forceinline__ unsigned short f2bf(float f) {
    unsigned u = __float_as_uint(f);
    return (unsigned short)((u + 0x7FFFu + ((u >> 16) & 1u)) >> 16);
}
__device__ __forceinline__ float bf2f(unsigned short b) {
    return __uint_as_float((unsigned)b << 16);
}
__device__ __forceinline__ unsigned cvt_pk_bf16(float a, float b) {
    unsigned r;
    asm("v_cvt_pk_bf16_f32 %0, %1, %2" : "=v"(r) : "v"(a), "v"(b));
    return r;   // lo16 = bf16(a), hi16 = bf16(b), RNE
}
#define VFMA2(a, b, c) __builtin_elementwise_fma((a), (b), (c))

// packed unitstep for this lane's 2 units (float2 lanes = units u0,u1).
// ei..eo = 2^(scaled pre-acts). i=1/(1+ei), f=1/(1+ef), g=(1-qg)/(1+qg),
// o=1/(1+eo); c'=f*c+i*g; h=o*tanh(c').  (r15-verified)
__device__ __forceinline__ void unitstep2(f32x2 ei, f32x2 ef, f32x2 qg, f32x2 eo,
                                          f32x2& c, f32x2& h) {
    const f32x2 one2 = {1.0f, 1.0f};
    f32x2 Ai  = ei + one2;
    f32x2 Af  = ef + one2;
    f32x2 Ao  = eo + one2;
    f32x2 P   = VFMA2(Ai, qg, Ai);             // Ai*(1+qg) = Ai*Ag
    f32x2 PAf = P * Af;
    f32x2 R   = {RCPF(PAf.x), RCPF(PAf.y)};
    f32x2 uu  = (one2 - qg) * Af;              // (1-qg)*Af
    f32x2 num = VFMA2(c, P, uu);               // c*P + (1-qg)*Af
    c = num * R;                               // = f*c + i*g
    f32x2 tq  = c * SCL_TANH;
    f32x2 qc  = {EXP2F(tq.x), EXP2F(tq.y)};
    f32x2 WAo = VFMA2(qc, Ao, Ao);             // (1+qc)*Ao
    f32x2 Rh  = {RCPF(WAo.x), RCPF(WAo.y)};
    h = (one2 - qc) * Rh;                      // = tanh(c') * o
}

__global__ __launch_bounds__(THREADS, 8) void lstm_mfma(
    const float* __restrict__ x, const float* __restrict__ W_ih,
    const float* __restrict__ W_hh, const float* __restrict__ b_ih,
    const float* __restrict__ b_hh, const float* __restrict__ W_fc,
    const float* __restrict__ b_fc, float* __restrict__ out)
{
    __shared__ __align__(16) char  s_buf[WPB * WAVE_LDS];
    __shared__ __align__(16) float s_zero[4];
    __shared__ __align__(16) float s_wfc[T][4][4];  // [t][grp][c0u0,c0u1,c1u0,c1u1]

    const int tid  = threadIdx.x;
    const int wv   = tid >> 6;
    const int lane = tid & 63;
    const int e    = lane & 15;     // elem col (B/C) and A-row index
    const int grp  = lane >> 4;

    char* sw = s_buf + wv * WAVE_LDS;

    // ---- zero h region (512 B = 128 dwords) + zero16 ----
    ((unsigned*)(sw + 2048))[lane] = 0u;
    ((unsigned*)(sw + 2048))[lane + 64] = 0u;
    if (tid < 4) s_zero[tid] = 0.0f;

    // ---- stage W_fc: s_wfc[t][g][j]: cls=j>>1, unit=2g+(j&1) ----
    for (int q = tid; q < T * 16; q += THREADS) {
        int t = q >> 4, rem = q & 15;
        int g = rem >> 2, j = rem & 3;
        int cls = j >> 1, uu = 2 * g + (j & 1);
        ((float*)s_wfc)[q] = W_fc[cls * (T * 8) + t * 8 + uu];
    }

    // ---- pack A fragments (hi in k0-15, lo in k16-31) + bias C-in (r5 map) ----
    const int au = e >> 1, ap = e & 1;
    const int row0 = ap * 8 + au;           // i (p=0) or f (p=1)  — both sigmoid
    const int row1 = 16 + ap * 8 + au;      // g (p=0, tanh) or o (p=1, sigmoid)
    const float sc1 = ap ? SCL_SIG : SCL_TANH;
    short8v A0, A1;
    #pragma unroll
    for (int j = 0; j < 8; ++j) {
        int k = grp * 8 + j;
        int kk = k & 15;
        float w0 = 0.f, w1 = 0.f;
        if (kk < 5)       { w0 = W_ih[row0 * 5 + kk] * SCL_SIG; w1 = W_ih[row1 * 5 + kk] * sc1; }
        else if (kk >= 8) { w0 = W_hh[row0 * 8 + kk - 8] * SCL_SIG; w1 = W_hh[row1 * 8 + kk - 8] * sc1; }
        unsigned short b0 = f2bf(w0), b1 = f2bf(w1);
        if (k >= 16) { b0 = f2bf(w0 - bf2f(b0)); b1 = f2bf(w1 - bf2f(b1)); }
        A0[j] = (short)b0; A1[j] = (short)b1;
    }
    f32x4 bias0, bias1;
    #pragma unroll
    for (int jj = 0; jj < 4; ++jj) {
        int rc = grp * 4 + jj;
        int uc = rc >> 1, pc = rc & 1;
        int w0r = pc * 8 + uc, w1r = 16 + pc * 8 + uc;
        bias0[jj] = (b_ih[w0r] + b_hh[w0r]) * SCL_SIG;
        bias1[jj] = (b_ih[w1r] + b_hh[w1r]) * (pc ? SCL_SIG : SCL_TANH);
    }

    // ---- x staging: lane stages elem (lane>>2), timesteps 2*(lane&3)+{0,1} ----
    const int es = lane >> 2;
    const int rr = lane & 3;
    const float* xbase = x + (size_t)(blockIdx.x * EPB + wv * EPW + es) * 240 + rr * 10;
    float xr[10];

    auto loadC = [&](int c) {
        const float2* p = (const float2*)(xbase + c * 40);
        #pragma unroll
        for (int q = 0; q < 5; ++q) { float2 v = p[q]; xr[2 * q] = v.x; xr[2 * q + 1] = v.y; }
    };
    auto writeC = [&]() {
        #pragma unroll
        for (int p2 = 0; p2 < 2; ++p2) {
            unsigned ph01 = cvt_pk_bf16(xr[p2 * 5 + 0], xr[p2 * 5 + 1]);
            unsigned ph23 = cvt_pk_bf16(xr[p2 * 5 + 2], xr[p2 * 5 + 3]);
            unsigned ph4  = cvt_pk_bf16(xr[p2 * 5 + 4], 0.0f);
            u32x4 hv = {ph01, ph23, ph4, 0u};
            int tl = 2 * rr + p2;
            *(u32x4*)(sw + tl * 256 + es * 16) = hv;
        }
    };

    loadC(0);
    writeC();
    __syncthreads();    // s_wfc / s_zero visibility (x,h regions wave-private)

    // ---- loop-invariant merged fragment pointers (r5/r16 form) ----
    const bool isX = (grp & 1) == 0;    // grp 0,2 read x rows; grp 1,3 read h row
    const char* pH0 = isX ? (sw + e * 16) : (sw + 2048 + e * 16);
    const char* pL0 = isX ? (const char*)s_zero : (sw + 2304 + e * 16);
    const int stepB = isX ? 256 : 0;
    unsigned* hwp = (unsigned*)(sw + 2048 + e * 16 + grp * 4);   // hi; +64 dw = lo

    f32x2 c2 = {0.f, 0.f};
    f32x2 ac0 = {0.f, 0.f}, ac1 = {0.f, 0.f};

    #pragma unroll 1
    for (int c = 0; c < NCH; ++c) {
        if (c + 1 < NCH) loadC(c + 1);
        const char* pH = pH0;

        #pragma unroll
        for (int u = 0; u < CH; ++u) {
            union { short8v v; u32x4 q; } bh, bl;
            bh.q = *(const u32x4*)pH;     // grp0,2: x row ; grp1,3: h_hi
            bl.q = *(const u32x4*)pL0;    // grp0,2: zero16 ; grp1,3: h_lo

            f32x4 g0 = __builtin_amdgcn_mfma_f32_16x16x32_bf16(A0, bh.v, bias0, 0, 0, 0);
            f32x4 g1 = __builtin_amdgcn_mfma_f32_16x16x32_bf16(A1, bh.v, bias1, 0, 0, 0);
            g0 = __builtin_amdgcn_mfma_f32_16x16x32_bf16(A0, bl.v, g0, 0, 0, 0);
            g1 = __builtin_amdgcn_mfma_f32_16x16x32_bf16(A1, bl.v, g1, 0, 0, 0);

            // this lane's 2 units: u0 = (g0[0],g0[1],g1[0],g1[1]), u1 = ([2],[3])
            f32x2 ei2 = {EXP2F(g0[0]), EXP2F(g0[2])};
            f32x2 ef2 = {EXP2F(g0[1]), EXP2F(g0[3])};
            f32x2 qg2 = {EXP2F(g1[0]), EXP2F(g1[2])};
            f32x2 eo2 = {EXP2F(g1[1]), EXP2F(g1[3])};

            f32x2 h2;
            unitstep2(ei2, ef2, qg2, eo2, c2, h2);

            // FC partials: 2 packed fma (cls0 and cls1, pairs over units)
            int t = c * CH + u;
            f32x2 w0 = *(const f32x2*)&s_wfc[t][grp][0];
            f32x2 w1 = *(const f32x2*)&s_wfc[t][grp][2];
            ac0 = VFMA2(w0, h2, ac0);
            ac1 = VFMA2(w1, h2, ac1);

            // pack h (hi + residual lo), publish to the wave's h rows
            unsigned pkh = cvt_pk_bf16(h2.x, h2.y);
            f32x2 b2 = {__uint_as_float(pkh << 16), __uint_as_float(pkh & 0xFFFF0000u)};
            f32x2 e2 = h2 - b2;
            unsigned pkl = cvt_pk_bf16(e2.x, e2.y);
            hwp[0]  = pkh;
            hwp[64] = pkl;

            pH += stepB;
        }
        if (c + 1 < NCH) writeC();
    }

    // ---- reduce FC partials across the 4 grps (lanes e, e+16, e+32, e+48) ----
    float o0 = ac0.x + ac0.y;
    float o1 = ac1.x + ac1.y;
    o0 += __shfl_xor(o0, 16); o0 += __shfl_xor(o0, 32);
    o1 += __shfl_xor(o1, 16); o1 += __shfl_xor(o1, 32);
    if (grp == 0) {
        int gb = blockIdx.x * EPB + wv * EPW + e;
        float2 o;
        o.x = o0 + b_fc[0];
        o.y = o1 + b_fc[1];
        *(float2*)&out[(size_t)gb * 2] = o;
    }
}

extern "C" void kernel_launch(void* const* d_in, const int* in_sizes, int n_in,
                              void* d_out, int out_size, void* d_ws, size_t ws_size,
                              hipStream_t stream) {
    const float* x    = (const float*)d_in[0];
    const float* W_ih = (const float*)d_in[1];
    const float* W_hh = (const float*)d_in[2];
    const float* b_ih = (const float*)d_in[3];
    const float* b_hh = (const float*)d_in[4];
    const float* W_fc = (const float*)d_in[5];
    const float* b_fc = (const float*)d_in[6];
    float* out = (float*)d_out;

    const int B = in_sizes[0] / 240;        // 131072
    dim3 grid(B / EPB), block(THREADS);     // 4096 blocks x 128 threads
    lstm_mfma<<<grid, block, 0, stream>>>(x, W_ih, W_hh, b_ih, b_hh, W_fc, b_fc, out);
}

// Round 18
// 65.906 us; speedup vs baseline: 2.4614x; 2.4614x over previous
//
#include <hip/hip_runtime.h>

// LSTM fused forward: B=131072, T=48, I=5, H=8, classes=2.
// Round-18 = round-17 VERBATIM minus the __launch_bounds__ min-waves arg.
// r17's 208us was pure VGPR-cap spill (VGPR 32, WRITE_SIZE 388MB — same
// signature as r4; occupancy DID reach 78%). r5 proved this EPW=16 skeleton
// fits 64 VGPR naturally -> 7-8 waves/SIMD uncoerced.
// Structure: 16x16x32 MFMA, 8192 waves (2x r16 residency); r5-verified
// A/bias/C maps; hi/lo W+h via [Bhi|Bhi]/[Blo|Blo] passes; x single-bf16;
// LDS-h merged divergent pointers (r16-verified); packed-f32 unitstep/FC
// (r15-verified); CH=8 single x buffer.

#define T 48
#define CH 8
#define NCH (T / CH)
#define EPW 16              // elems per wave
#define WPB 2
#define EPB (EPW * WPB)     // 32
#define THREADS (64 * WPB)
#define WAVE_LDS 2560       // 2048 x (8 rows x 16 elems x 16B) | 256 h_hi | 256 h_lo

typedef __attribute__((ext_vector_type(8))) short    short8v;
typedef __attribute__((ext_vector_type(2))) float    f32x2;
typedef __attribute__((ext_vector_type(4))) float    f32x4;
typedef __attribute__((ext_vector_type(4))) unsigned u32x4;

#if __has_builtin(__builtin_amdgcn_exp2f)
#define EXP2F(x) __builtin_amdgcn_exp2f(x)
#else
#define EXP2F(x) exp2f(x)
#endif
#if __has_builtin(__builtin_amdgcn_rcpf)
#define RCPF(x) __builtin_amdgcn_rcpf(x)
#else
#define RCPF(x) (1.0f / (x))
#endif

#define SCL_SIG  (-1.44269504f)   // sigmoid gates: e = 2^(scl*v)
#define SCL_TANH (-2.88539008f)   // tanh gates:    q = 2^(scl*v)

__device__ __forceinline__ unsigned short f2bf(float f) {
    unsigned u = __float_as_uint(f);
    return (unsigned short)((u + 0x7FFFu + ((u >> 16) & 1u)) >> 16);
}
__device__ __forceinline__ float bf2f(unsigned short b) {
    return __uint_as_float((unsigned)b << 16);
}
__device__ __forceinline__ unsigned cvt_pk_bf16(float a, float b) {
    unsigned r;
    asm("v_cvt_pk_bf16_f32 %0, %1, %2" : "=v"(r) : "v"(a), "v"(b));
    return r;   // lo16 = bf16(a), hi16 = bf16(b), RNE
}
#define VFMA2(a, b, c) __builtin_elementwise_fma((a), (b), (c))

// packed unitstep for this lane's 2 units (float2 lanes = units u0,u1).
// ei..eo = 2^(scaled pre-acts). i=1/(1+ei), f=1/(1+ef), g=(1-qg)/(1+qg),
// o=1/(1+eo); c'=f*c+i*g; h=o*tanh(c').  (r15-verified)
__device__ __forceinline__ void unitstep2(f32x2 ei, f32x2 ef, f32x2 qg, f32x2 eo,
                                          f32x2& c, f32x2& h) {
    const f32x2 one2 = {1.0f, 1.0f};
    f32x2 Ai  = ei + one2;
    f32x2 Af  = ef + one2;
    f32x2 Ao  = eo + one2;
    f32x2 P   = VFMA2(Ai, qg, Ai);             // Ai*(1+qg) = Ai*Ag
    f32x2 PAf = P * Af;
    f32x2 R   = {RCPF(PAf.x), RCPF(PAf.y)};
    f32x2 uu  = (one2 - qg) * Af;              // (1-qg)*Af
    f32x2 num = VFMA2(c, P, uu);               // c*P + (1-qg)*Af
    c = num * R;                               // = f*c + i*g
    f32x2 tq  = c * SCL_TANH;
    f32x2 qc  = {EXP2F(tq.x), EXP2F(tq.y)};
    f32x2 WAo = VFMA2(qc, Ao, Ao);             // (1+qc)*Ao
    f32x2 Rh  = {RCPF(WAo.x), RCPF(WAo.y)};
    h = (one2 - qc) * Rh;                      // = tanh(c') * o
}

__global__ __launch_bounds__(THREADS) void lstm_mfma(
    const float* __restrict__ x, const float* __restrict__ W_ih,
    const float* __restrict__ W_hh, const float* __restrict__ b_ih,
    const float* __restrict__ b_hh, const float* __restrict__ W_fc,
    const float* __restrict__ b_fc, float* __restrict__ out)
{
    __shared__ __align__(16) char  s_buf[WPB * WAVE_LDS];
    __shared__ __align__(16) float s_zero[4];
    __shared__ __align__(16) float s_wfc[T][4][4];  // [t][grp][c0u0,c0u1,c1u0,c1u1]

    const int tid  = threadIdx.x;
    const int wv   = tid >> 6;
    const int lane = tid & 63;
    const int e    = lane & 15;     // elem col (B/C) and A-row index
    const int grp  = lane >> 4;

    char* sw = s_buf + wv * WAVE_LDS;

    // ---- zero h region (512 B = 128 dwords) + zero16 ----
    ((unsigned*)(sw + 2048))[lane] = 0u;
    ((unsigned*)(sw + 2048))[lane + 64] = 0u;
    if (tid < 4) s_zero[tid] = 0.0f;

    // ---- stage W_fc: s_wfc[t][g][j]: cls=j>>1, unit=2g+(j&1) ----
    for (int q = tid; q < T * 16; q += THREADS) {
        int t = q >> 4, rem = q & 15;
        int g = rem >> 2, j = rem & 3;
        int cls = j >> 1, uu = 2 * g + (j & 1);
        ((float*)s_wfc)[q] = W_fc[cls * (T * 8) + t * 8 + uu];
    }

    // ---- pack A fragments (hi in k0-15, lo in k16-31) + bias C-in (r5 map) ----
    const int au = e >> 1, ap = e & 1;
    const int row0 = ap * 8 + au;           // i (p=0) or f (p=1)  — both sigmoid
    const int row1 = 16 + ap * 8 + au;      // g (p=0, tanh) or o (p=1, sigmoid)
    const float sc1 = ap ? SCL_SIG : SCL_TANH;
    short8v A0, A1;
    #pragma unroll
    for (int j = 0; j < 8; ++j) {
        int k = grp * 8 + j;
        int kk = k & 15;
        float w0 = 0.f, w1 = 0.f;
        if (kk < 5)       { w0 = W_ih[row0 * 5 + kk] * SCL_SIG; w1 = W_ih[row1 * 5 + kk] * sc1; }
        else if (kk >= 8) { w0 = W_hh[row0 * 8 + kk - 8] * SCL_SIG; w1 = W_hh[row1 * 8 + kk - 8] * sc1; }
        unsigned short b0 = f2bf(w0), b1 = f2bf(w1);
        if (k >= 16) { b0 = f2bf(w0 - bf2f(b0)); b1 = f2bf(w1 - bf2f(b1)); }
        A0[j] = (short)b0; A1[j] = (short)b1;
    }
    f32x4 bias0, bias1;
    #pragma unroll
    for (int jj = 0; jj < 4; ++jj) {
        int rc = grp * 4 + jj;
        int uc = rc >> 1, pc = rc & 1;
        int w0r = pc * 8 + uc, w1r = 16 + pc * 8 + uc;
        bias0[jj] = (b_ih[w0r] + b_hh[w0r]) * SCL_SIG;
        bias1[jj] = (b_ih[w1r] + b_hh[w1r]) * (pc ? SCL_SIG : SCL_TANH);
    }

    // ---- x staging: lane stages elem (lane>>2), timesteps 2*(lane&3)+{0,1} ----
    const int es = lane >> 2;
    const int rr = lane & 3;
    const float* xbase = x + (size_t)(blockIdx.x * EPB + wv * EPW + es) * 240 + rr * 10;
    float xr[10];

    auto loadC = [&](int c) {
        const float2* p = (const float2*)(xbase + c * 40);
        #pragma unroll
        for (int q = 0; q < 5; ++q) { float2 v = p[q]; xr[2 * q] = v.x; xr[2 * q + 1] = v.y; }
    };
    auto writeC = [&]() {
        #pragma unroll
        for (int p2 = 0; p2 < 2; ++p2) {
            unsigned ph01 = cvt_pk_bf16(xr[p2 * 5 + 0], xr[p2 * 5 + 1]);
            unsigned ph23 = cvt_pk_bf16(xr[p2 * 5 + 2], xr[p2 * 5 + 3]);
            unsigned ph4  = cvt_pk_bf16(xr[p2 * 5 + 4], 0.0f);
            u32x4 hv = {ph01, ph23, ph4, 0u};
            int tl = 2 * rr + p2;
            *(u32x4*)(sw + tl * 256 + es * 16) = hv;
        }
    };

    loadC(0);
    writeC();
    __syncthreads();    // s_wfc / s_zero visibility (x,h regions wave-private)

    // ---- loop-invariant merged fragment pointers (r5/r16 form) ----
    const bool isX = (grp & 1) == 0;    // grp 0,2 read x rows; grp 1,3 read h row
    const char* pH0 = isX ? (sw + e * 16) : (sw + 2048 + e * 16);
    const char* pL0 = isX ? (const char*)s_zero : (sw + 2304 + e * 16);
    const int stepB = isX ? 256 : 0;
    unsigned* hwp = (unsigned*)(sw + 2048 + e * 16 + grp * 4);   // hi; +64 dw = lo

    f32x2 c2 = {0.f, 0.f};
    f32x2 ac0 = {0.f, 0.f}, ac1 = {0.f, 0.f};

    #pragma unroll 1
    for (int c = 0; c < NCH; ++c) {
        if (c + 1 < NCH) loadC(c + 1);
        const char* pH = pH0;

        #pragma unroll
        for (int u = 0; u < CH; ++u) {
            union { short8v v; u32x4 q; } bh, bl;
            bh.q = *(const u32x4*)pH;     // grp0,2: x row ; grp1,3: h_hi
            bl.q = *(const u32x4*)pL0;    // grp0,2: zero16 ; grp1,3: h_lo

            f32x4 g0 = __builtin_amdgcn_mfma_f32_16x16x32_bf16(A0, bh.v, bias0, 0, 0, 0);
            f32x4 g1 = __builtin_amdgcn_mfma_f32_16x16x32_bf16(A1, bh.v, bias1, 0, 0, 0);
            g0 = __builtin_amdgcn_mfma_f32_16x16x32_bf16(A0, bl.v, g0, 0, 0, 0);
            g1 = __builtin_amdgcn_mfma_f32_16x16x32_bf16(A1, bl.v, g1, 0, 0, 0);

            // this lane's 2 units: u0 = (g0[0],g0[1],g1[0],g1[1]), u1 = ([2],[3])
            f32x2 ei2 = {EXP2F(g0[0]), EXP2F(g0[2])};
            f32x2 ef2 = {EXP2F(g0[1]), EXP2F(g0[3])};
            f32x2 qg2 = {EXP2F(g1[0]), EXP2F(g1[2])};
            f32x2 eo2 = {EXP2F(g1[1]), EXP2F(g1[3])};

            f32x2 h2;
            unitstep2(ei2, ef2, qg2, eo2, c2, h2);

            // FC partials: 2 packed fma (cls0 and cls1, pairs over units)
            int t = c * CH + u;
            f32x2 w0 = *(const f32x2*)&s_wfc[t][grp][0];
            f32x2 w1 = *(const f32x2*)&s_wfc[t][grp][2];
            ac0 = VFMA2(w0, h2, ac0);
            ac1 = VFMA2(w1, h2, ac1);

            // pack h (hi + residual lo), publish to the wave's h rows
            unsigned pkh = cvt_pk_bf16(h2.x, h2.y);
            f32x2 b2 = {__uint_as_float(pkh << 16), __uint_as_float(pkh & 0xFFFF0000u)};
            f32x2 e2 = h2 - b2;
            unsigned pkl = cvt_pk_bf16(e2.x, e2.y);
            hwp[0]  = pkh;
            hwp[64] = pkl;

            pH += stepB;
        }
        if (c + 1 < NCH) writeC();
    }

    // ---- reduce FC partials across the 4 grps (lanes e, e+16, e+32, e+48) ----
    float o0 = ac0.x + ac0.y;
    float o1 = ac1.x + ac1.y;
    o0 += __shfl_xor(o0, 16); o0 += __shfl_xor(o0, 32);
    o1 += __shfl_xor(o1, 16); o1 += __shfl_xor(o1, 32);
    if (grp == 0) {
        int gb = blockIdx.x * EPB + wv * EPW + e;
        float2 o;
        o.x = o0 + b_fc[0];
        o.y = o1 + b_fc[1];
        *(float2*)&out[(size_t)gb * 2] = o;
    }
}

extern "C" void kernel_launch(void* const* d_in, const int* in_sizes, int n_in,
                              void* d_out, int out_size, void* d_ws, size_t ws_size,
                              hipStream_t stream) {
    const float* x    = (const float*)d_in[0];
    const float* W_ih = (const float*)d_in[1];
    const float* W_hh = (const float*)d_in[2];
    const float* b_ih = (const float*)d_in[3];
    const float* b_hh = (const float*)d_in[4];
    const float* W_fc = (const float*)d_in[5];
    const float* b_fc = (const float*)d_in[6];
    float* out = (float*)d_out;

    const int B = in_sizes[0] / 240;        // 131072
    dim3 grid(B / EPB), block(THREADS);     // 4096 blocks x 128 threads
    lstm_mfma<<<grid, block, 0, stream>>>(x, W_ih, W_hh, b_ih, b_hh, W_fc, b_fc, out);
}

// Round 19
// 59.739 us; speedup vs baseline: 2.7154x; 1.1032x over previous
//
#include <hip/hip_runtime.h>

// LSTM fused forward: B=131072, T=48, I=5, H=8, classes=2.
// Round-19 = round-16 (verified best, 59.3us, absmax 1.95e-3: 32x32x16 bf16
// MFMA x3 hi/lo W+h, x single-bf16, LDS-h merged divergent pointers,
// compiler-packed f32 math) with ONE change: pairwise-batched reciprocals.
//   The two unit-pairs' R (and Rh) denominators are combined:
//   r = rcp(a*b); 1/a = r*b; 1/b = r*a  ->  8 rcp/step -> 4 rcp + 6 pk-mul.
//   Overflow-safe: PAf <= 2^46/unit even fully saturated (|preact|<=8);
//   pair product <= 2^92 < 2^127.
// r18 settled the occupancy question: 2x waves at +8% issue = +11% wall ->
// issue-bound; instruction deletion is the only lever.

#define T 48
#define CH 4
#define NCH (T / CH)
#define EPW 32              // elems per wave
#define WPB 2
#define EPB (EPW * WPB)     // 64
#define THREADS (64 * WPB)
#define WAVE_LDS 3072       // 2048 x | 512 h_hi | 512 h_lo

typedef __attribute__((ext_vector_type(8)))  short    short8v;
typedef __attribute__((ext_vector_type(2)))  float    f32x2;
typedef __attribute__((ext_vector_type(4)))  float    f32x4;
typedef __attribute__((ext_vector_type(16))) float    f32x16;
typedef __attribute__((ext_vector_type(2)))  unsigned u32x2;
typedef __attribute__((ext_vector_type(4)))  unsigned u32x4;

#if __has_builtin(__builtin_amdgcn_exp2f)
#define EXP2F(x) __builtin_amdgcn_exp2f(x)
#else
#define EXP2F(x) exp2f(x)
#endif
#if __has_builtin(__builtin_amdgcn_rcpf)
#define RCPF(x) __builtin_amdgcn_rcpf(x)
#else
#define RCPF(x) (1.0f / (x))
#endif

#define SCL_SIG  (-1.44269504f)   // sigmoid gates: e = 2^(scl*v)
#define SCL_TANH (-2.88539008f)   // tanh gates:    q = 2^(scl*v)

__device__ __forceinline__ unsigned short f2bf(float f) {
    unsigned u = __float_as_uint(f);
    return (unsigned short)((u + 0x7FFFu + ((u >> 16) & 1u)) >> 16);
}
__device__ __forceinline__ float bf2f(unsigned short b) {
    return __uint_as_float((unsigned)b << 16);
}
__device__ __forceinline__ unsigned cvt_pk_bf16(float a, float b) {
    unsigned r;
    asm("v_cvt_pk_bf16_f32 %0, %1, %2" : "=v"(r) : "v"(a), "v"(b));
    return r;   // lo16 = bf16(a), hi16 = bf16(b), RNE
}
#define VFMA2(a, b, c) __builtin_elementwise_fma((a), (b), (c))

__global__ __launch_bounds__(THREADS) void lstm_mfma(
    const float* __restrict__ x, const float* __restrict__ W_ih,
    const float* __restrict__ W_hh, const float* __restrict__ b_ih,
    const float* __restrict__ b_hh, const float* __restrict__ W_fc,
    const float* __restrict__ b_fc, float* __restrict__ out)
{
    __shared__ __align__(16) char  s_buf[WPB * WAVE_LDS];
    __shared__ __align__(16) float s_zero[4];
    __shared__ __align__(16) float s_wfc[T][16];   // [t][khalf*8 + cls*4 + u]

    const int tid  = threadIdx.x;
    const int wv   = tid >> 6;
    const int lane = tid & 63;
    const int m    = lane & 31;      // A-row / B-col / C-col (elem)
    const int khalf = lane >> 5;     // k = khalf*8 + j
    const bool isHi = (khalf == 1);

    char* sw = s_buf + wv * WAVE_LDS;

    // ---- zero h region (1024 B = 64 lanes x 16 B) + zero16 ----
    {
        u32x4 z = {0u, 0u, 0u, 0u};
        *(u32x4*)(sw + 2048 + lane * 16) = z;
        if (tid < 4) s_zero[tid] = 0.0f;
    }

    // ---- stage W_fc: [t][half*8 + cls*4 + u] = W_fc[cls][t*8 + half*4 + u] ----
    for (int q = tid; q < T * 16; q += THREADS) {
        int t = q >> 4, rem = q & 15;
        int half = rem >> 3, cls = (rem >> 2) & 1, u = rem & 3;
        s_wfc[t][rem] = W_fc[cls * (T * 8) + t * 8 + half * 4 + u];
    }

    // ---- pack A fragments (hi + lo) ----
    // row m: 0-7=i, 8-15=f, 16-23=g, 24-31=o (W memory order)
    const float sclA = (m >= 16 && m < 24) ? SCL_TANH : SCL_SIG;
    short8v Ah, Al;
    #pragma unroll
    for (int j = 0; j < 8; ++j) {
        int k = khalf * 8 + j;
        float w = 0.f;
        if (k < 5)       w = W_ih[m * 5 + k];
        else if (k >= 8) w = W_hh[m * 8 + (k - 8)];
        w *= sclA;
        unsigned short bhh = f2bf(w);
        unsigned short bll = f2bf(w - bf2f(bhh));
        Ah[j] = (short)bhh; Al[j] = (short)bll;
    }
    // ---- bias C-in, in C layout ----
    f32x16 biasc;
    #pragma unroll
    for (int r = 0; r < 16; ++r) {
        int row = (r & 3) + 8 * (r >> 2) + 4 * khalf;
        float s = (row >= 16 && row < 24) ? SCL_TANH : SCL_SIG;
        biasc[r] = (b_ih[row] + b_hh[row]) * s;
    }

    // ---- x staging: lane stages elem (lane>>1), t-pair (lane&1) of chunk ----
    const int es = lane >> 1;
    const int tp = lane & 1;
    const float* xbase = x + (size_t)(blockIdx.x * EPB + wv * EPW + es) * 240 + tp * 10;
    float xr[10];

    auto loadC = [&](int c) {
        const float2* p = (const float2*)(xbase + c * 20);
        #pragma unroll
        for (int q = 0; q < 5; ++q) { float2 v = p[q]; xr[2 * q] = v.x; xr[2 * q + 1] = v.y; }
    };
    auto writeC = [&]() {
        #pragma unroll
        for (int p2 = 0; p2 < 2; ++p2) {
            unsigned ph01 = cvt_pk_bf16(xr[p2 * 5 + 0], xr[p2 * 5 + 1]);
            unsigned ph23 = cvt_pk_bf16(xr[p2 * 5 + 2], xr[p2 * 5 + 3]);
            unsigned ph4  = cvt_pk_bf16(xr[p2 * 5 + 4], 0.0f);
            u32x4 hv = {ph01, ph23, ph4, 0u};
            int tl = 2 * tp + p2;
            *(u32x4*)(sw + tl * 512 + es * 16) = hv;
        }
    };

    loadC(0);
    writeC();
    __syncthreads();    // s_wfc / s_zero visibility (x,h regions wave-private)

    // ---- loop-invariant merged fragment pointers ----
    const int mofs = m * 16;
    const char* bhp0 = isHi ? (sw + 2048 + mofs) : (sw + mofs);
    const char* bhp1 = isHi ? (sw + 2048 + mofs) : (sw + 512 + mofs);
    const char* bhp2 = isHi ? (sw + 2048 + mofs) : (sw + 1024 + mofs);
    const char* bhp3 = isHi ? (sw + 2048 + mofs) : (sw + 1536 + mofs);
    const char* blp  = isHi ? (sw + 2560 + mofs) : (const char*)s_zero;
    char* whH = sw + 2048 + mofs + khalf * 8;   // this lane's 8B h slot (hi plane)
    char* whL = whH + 512;                      // lo plane

    const f32x2 one2 = {1.0f, 1.0f};
    f32x2 c01 = {0.f, 0.f}, c23 = {0.f, 0.f};
    f32x2 ac0 = {0.f, 0.f}, ac1 = {0.f, 0.f};

    #pragma unroll 1
    for (int c = 0; c < NCH; ++c) {
        if (c + 1 < NCH) loadC(c + 1);

        #pragma unroll
        for (int u = 0; u < CH; ++u) {
            const char* bp = (u == 0) ? bhp0 : (u == 1) ? bhp1 : (u == 2) ? bhp2 : bhp3;
            union { short8v v; u32x4 q; } bh, bl;
            bh.q = *(const u32x4*)bp;     // lo lanes: x row ; hi lanes: h_hi
            bl.q = *(const u32x4*)blp;    // lo lanes: zero16 ; hi lanes: h_lo

            f32x16 g = __builtin_amdgcn_mfma_f32_32x32x16_bf16(Ah, bh.v, biasc, 0, 0, 0);
            g = __builtin_amdgcn_mfma_f32_32x32x16_bf16(Ah, bl.v, g, 0, 0, 0);
            g = __builtin_amdgcn_mfma_f32_32x32x16_bf16(Al, bh.v, g, 0, 0, 0);

            f32x2 ei01 = {EXP2F(g[0]),  EXP2F(g[1])};
            f32x2 ei23 = {EXP2F(g[2]),  EXP2F(g[3])};
            f32x2 ef01 = {EXP2F(g[4]),  EXP2F(g[5])};
            f32x2 ef23 = {EXP2F(g[6]),  EXP2F(g[7])};
            f32x2 qg01 = {EXP2F(g[8]),  EXP2F(g[9])};
            f32x2 qg23 = {EXP2F(g[10]), EXP2F(g[11])};
            f32x2 eo01 = {EXP2F(g[12]), EXP2F(g[13])};
            f32x2 eo23 = {EXP2F(g[14]), EXP2F(g[15])};

            // ---- merged dual unitstep, pairwise-batched reciprocals ----
            f32x2 Ai_a = ei01 + one2, Af_a = ef01 + one2, Ao_a = eo01 + one2;
            f32x2 Ai_b = ei23 + one2, Af_b = ef23 + one2, Ao_b = eo23 + one2;
            f32x2 P_a = VFMA2(Ai_a, qg01, Ai_a);          // Ai*Ag
            f32x2 P_b = VFMA2(Ai_b, qg23, Ai_b);
            f32x2 PAf_a = P_a * Af_a;
            f32x2 PAf_b = P_b * Af_b;
            f32x2 pr = PAf_a * PAf_b;                     // <= 2^92, safe
            f32x2 rr = {RCPF(pr.x), RCPF(pr.y)};
            f32x2 R_a = rr * PAf_b;
            f32x2 R_b = rr * PAf_a;
            f32x2 num_a = VFMA2(c01, P_a, (one2 - qg01) * Af_a);
            f32x2 num_b = VFMA2(c23, P_b, (one2 - qg23) * Af_b);
            c01 = num_a * R_a;                            // = f*c + i*g
            c23 = num_b * R_b;
            f32x2 tq_a = c01 * SCL_TANH;
            f32x2 tq_b = c23 * SCL_TANH;
            f32x2 qc_a = {EXP2F(tq_a.x), EXP2F(tq_a.y)};
            f32x2 qc_b = {EXP2F(tq_b.x), EXP2F(tq_b.y)};
            f32x2 W_a = VFMA2(qc_a, Ao_a, Ao_a);          // (1+qc)*Ao
            f32x2 W_b = VFMA2(qc_b, Ao_b, Ao_b);
            f32x2 pr2 = W_a * W_b;                        // <= 2^69, safe
            f32x2 rr2 = {RCPF(pr2.x), RCPF(pr2.y)};
            f32x2 h01 = ((one2 - qc_a) * W_b) * rr2;      // = tanh(c')*o
            f32x2 h23 = ((one2 - qc_b) * W_a) * rr2;

            // FC partials: float2 fma (compiler packs)
            int t = c * CH + u;
            f32x4 w0 = *(const f32x4*)&s_wfc[t][khalf * 8];       // cls0 u0-3
            f32x4 w1 = *(const f32x4*)&s_wfc[t][khalf * 8 + 4];   // cls1 u0-3
            f32x2 w0a = {w0[0], w0[1]}, w0b = {w0[2], w0[3]};
            f32x2 w1a = {w1[0], w1[1]}, w1b = {w1[2], w1[3]};
            ac0 = VFMA2(w0a, h01, ac0);
            ac0 = VFMA2(w0b, h23, ac0);
            ac1 = VFMA2(w1a, h01, ac1);
            ac1 = VFMA2(w1b, h23, ac1);

            // pack h (hi + residual lo) and publish to the wave's h rows
            unsigned p01 = cvt_pk_bf16(h01.x, h01.y);
            unsigned p23 = cvt_pk_bf16(h23.x, h23.y);
            f32x2 b01 = {__uint_as_float(p01 << 16), __uint_as_float(p01 & 0xFFFF0000u)};
            f32x2 b23 = {__uint_as_float(p23 << 16), __uint_as_float(p23 & 0xFFFF0000u)};
            f32x2 e01 = h01 - b01;
            f32x2 e23 = h23 - b23;
            unsigned q01 = cvt_pk_bf16(e01.x, e01.y);
            unsigned q23 = cvt_pk_bf16(e23.x, e23.y);
            u32x2 wh = {p01, p23};
            u32x2 wl = {q01, q23};
            *(u32x2*)whH = wh;
            *(u32x2*)whL = wl;
        }
        if (c + 1 < NCH) writeC();
    }

    // ---- combine units 0-3 (lane m) and 4-7 (lane m+32), write out ----
    float o0 = ac0.x + ac0.y;
    float o1 = ac1.x + ac1.y;
    o0 += __shfl_xor(o0, 32);
    o1 += __shfl_xor(o1, 32);
    if (!isHi) {
        int gb = blockIdx.x * EPB + wv * EPW + m;
        float2 o;
        o.x = o0 + b_fc[0];
        o.y = o1 + b_fc[1];
        *(float2*)&out[(size_t)gb * 2] = o;
    }
}

extern "C" void kernel_launch(void* const* d_in, const int* in_sizes, int n_in,
                              void* d_out, int out_size, void* d_ws, size_t ws_size,
                              hipStream_t stream) {
    const float* x    = (const float*)d_in[0];
    const float* W_ih = (const float*)d_in[1];
    const float* W_hh = (const float*)d_in[2];
    const float* b_ih = (const float*)d_in[3];
    const float* b_hh = (const float*)d_in[4];
    const float* W_fc = (const float*)d_in[5];
    const float* b_fc = (const float*)d_in[6];
    float* out = (float*)d_out;

    const int B = in_sizes[0] / 240;        // 131072
    dim3 grid(B / EPB), block(THREADS);
    lstm_mfma<<<grid, block, 0, stream>>>(x, W_ih, W_hh, b_ih, b_hh, W_fc, b_fc, out);
}

// Round 20
// 53.811 us; speedup vs baseline: 3.0146x; 1.1102x over previous
//
#include <hip/hip_runtime.h>

// LSTM fused forward: B=131072, T=48, I=5, H=8, classes=2.
// Round-20 = round-19 (59.7us, absmax 1.95e-3) with ONE change: h_lo residual
// plane DELETED (h stored single bf16; W stays hi/lo, x stays single).
//   => 2 MFMAs/step (Ah*B + Al*B), no residual pack, 1 ds_read + 1 ds_write
//   fewer per step. Predicted absmax 4-6e-3 (x_lo-drop cost +1e-3 measured
//   r3->r10; h is recurrent -> ~2-3x that). Threshold 8.125e-3.
// Pipe census at r19: VALU 57% + trans ~26% + MFMA 12% + DS ~5% — multi-pipe
// issue-saturated; only instruction deletion pays (r8/r18/r7/r15 evidence).

#define T 48
#define CH 4
#define NCH (T / CH)
#define EPW 32              // elems per wave
#define WPB 2
#define EPB (EPW * WPB)     // 64
#define THREADS (64 * WPB)
#define WAVE_LDS 2560       // 2048 x | 512 h (single bf16)

typedef __attribute__((ext_vector_type(8)))  short    short8v;
typedef __attribute__((ext_vector_type(2)))  float    f32x2;
typedef __attribute__((ext_vector_type(4)))  float    f32x4;
typedef __attribute__((ext_vector_type(16))) float    f32x16;
typedef __attribute__((ext_vector_type(2)))  unsigned u32x2;
typedef __attribute__((ext_vector_type(4)))  unsigned u32x4;

#if __has_builtin(__builtin_amdgcn_exp2f)
#define EXP2F(x) __builtin_amdgcn_exp2f(x)
#else
#define EXP2F(x) exp2f(x)
#endif
#if __has_builtin(__builtin_amdgcn_rcpf)
#define RCPF(x) __builtin_amdgcn_rcpf(x)
#else
#define RCPF(x) (1.0f / (x))
#endif

#define SCL_SIG  (-1.44269504f)   // sigmoid gates: e = 2^(scl*v)
#define SCL_TANH (-2.88539008f)   // tanh gates:    q = 2^(scl*v)

__device__ __forceinline__ unsigned short f2bf(float f) {
    unsigned u = __float_as_uint(f);
    return (unsigned short)((u + 0x7FFFu + ((u >> 16) & 1u)) >> 16);
}
__device__ __forceinline__ float bf2f(unsigned short b) {
    return __uint_as_float((unsigned)b << 16);
}
__device__ __forceinline__ unsigned cvt_pk_bf16(float a, float b) {
    unsigned r;
    asm("v_cvt_pk_bf16_f32 %0, %1, %2" : "=v"(r) : "v"(a), "v"(b));
    return r;   // lo16 = bf16(a), hi16 = bf16(b), RNE
}
#define VFMA2(a, b, c) __builtin_elementwise_fma((a), (b), (c))

__global__ __launch_bounds__(THREADS) void lstm_mfma(
    const float* __restrict__ x, const float* __restrict__ W_ih,
    const float* __restrict__ W_hh, const float* __restrict__ b_ih,
    const float* __restrict__ b_hh, const float* __restrict__ W_fc,
    const float* __restrict__ b_fc, float* __restrict__ out)
{
    __shared__ __align__(16) char  s_buf[WPB * WAVE_LDS];
    __shared__ __align__(16) float s_wfc[T][16];   // [t][khalf*8 + cls*4 + u]

    const int tid  = threadIdx.x;
    const int wv   = tid >> 6;
    const int lane = tid & 63;
    const int m    = lane & 31;      // A-row / B-col / C-col (elem)
    const int khalf = lane >> 5;     // k = khalf*8 + j
    const bool isHi = (khalf == 1);

    char* sw = s_buf + wv * WAVE_LDS;

    // ---- zero h region (512 B = 64 lanes x 8 B) ----
    {
        u32x2 z = {0u, 0u};
        *(u32x2*)(sw + 2048 + lane * 8) = z;
    }

    // ---- stage W_fc: [t][half*8 + cls*4 + u] = W_fc[cls][t*8 + half*4 + u] ----
    for (int q = tid; q < T * 16; q += THREADS) {
        int t = q >> 4, rem = q & 15;
        int half = rem >> 3, cls = (rem >> 2) & 1, u = rem & 3;
        s_wfc[t][rem] = W_fc[cls * (T * 8) + t * 8 + half * 4 + u];
    }

    // ---- pack A fragments (hi + lo) ----
    // row m: 0-7=i, 8-15=f, 16-23=g, 24-31=o (W memory order)
    const float sclA = (m >= 16 && m < 24) ? SCL_TANH : SCL_SIG;
    short8v Ah, Al;
    #pragma unroll
    for (int j = 0; j < 8; ++j) {
        int k = khalf * 8 + j;
        float w = 0.f;
        if (k < 5)       w = W_ih[m * 5 + k];
        else if (k >= 8) w = W_hh[m * 8 + (k - 8)];
        w *= sclA;
        unsigned short bhh = f2bf(w);
        unsigned short bll = f2bf(w - bf2f(bhh));
        Ah[j] = (short)bhh; Al[j] = (short)bll;
    }
    // ---- bias C-in, in C layout ----
    f32x16 biasc;
    #pragma unroll
    for (int r = 0; r < 16; ++r) {
        int row = (r & 3) + 8 * (r >> 2) + 4 * khalf;
        float s = (row >= 16 && row < 24) ? SCL_TANH : SCL_SIG;
        biasc[r] = (b_ih[row] + b_hh[row]) * s;
    }

    // ---- x staging: lane stages elem (lane>>1), t-pair (lane&1) of chunk ----
    const int es = lane >> 1;
    const int tp = lane & 1;
    const float* xbase = x + (size_t)(blockIdx.x * EPB + wv * EPW + es) * 240 + tp * 10;
    float xr[10];

    auto loadC = [&](int c) {
        const float2* p = (const float2*)(xbase + c * 20);
        #pragma unroll
        for (int q = 0; q < 5; ++q) { float2 v = p[q]; xr[2 * q] = v.x; xr[2 * q + 1] = v.y; }
    };
    auto writeC = [&]() {
        #pragma unroll
        for (int p2 = 0; p2 < 2; ++p2) {
            unsigned ph01 = cvt_pk_bf16(xr[p2 * 5 + 0], xr[p2 * 5 + 1]);
            unsigned ph23 = cvt_pk_bf16(xr[p2 * 5 + 2], xr[p2 * 5 + 3]);
            unsigned ph4  = cvt_pk_bf16(xr[p2 * 5 + 4], 0.0f);
            u32x4 hv = {ph01, ph23, ph4, 0u};
            int tl = 2 * tp + p2;
            *(u32x4*)(sw + tl * 512 + es * 16) = hv;
        }
    };

    loadC(0);
    writeC();
    __syncthreads();    // s_wfc visibility (x,h regions wave-private)

    // ---- loop-invariant merged fragment pointers ----
    const int mofs = m * 16;
    const char* bhp0 = isHi ? (sw + 2048 + mofs) : (sw + mofs);
    const char* bhp1 = isHi ? (sw + 2048 + mofs) : (sw + 512 + mofs);
    const char* bhp2 = isHi ? (sw + 2048 + mofs) : (sw + 1024 + mofs);
    const char* bhp3 = isHi ? (sw + 2048 + mofs) : (sw + 1536 + mofs);
    char* whH = sw + 2048 + mofs + khalf * 8;   // this lane's 8B h slot

    const f32x2 one2 = {1.0f, 1.0f};
    f32x2 c01 = {0.f, 0.f}, c23 = {0.f, 0.f};
    f32x2 ac0 = {0.f, 0.f}, ac1 = {0.f, 0.f};

    #pragma unroll 1
    for (int c = 0; c < NCH; ++c) {
        if (c + 1 < NCH) loadC(c + 1);

        #pragma unroll
        for (int u = 0; u < CH; ++u) {
            const char* bp = (u == 0) ? bhp0 : (u == 1) ? bhp1 : (u == 2) ? bhp2 : bhp3;
            union { short8v v; u32x4 q; } bh;
            bh.q = *(const u32x4*)bp;     // lo lanes: x row ; hi lanes: h (bf16)

            f32x16 g = __builtin_amdgcn_mfma_f32_32x32x16_bf16(Ah, bh.v, biasc, 0, 0, 0);
            g = __builtin_amdgcn_mfma_f32_32x32x16_bf16(Al, bh.v, g, 0, 0, 0);

            f32x2 ei01 = {EXP2F(g[0]),  EXP2F(g[1])};
            f32x2 ei23 = {EXP2F(g[2]),  EXP2F(g[3])};
            f32x2 ef01 = {EXP2F(g[4]),  EXP2F(g[5])};
            f32x2 ef23 = {EXP2F(g[6]),  EXP2F(g[7])};
            f32x2 qg01 = {EXP2F(g[8]),  EXP2F(g[9])};
            f32x2 qg23 = {EXP2F(g[10]), EXP2F(g[11])};
            f32x2 eo01 = {EXP2F(g[12]), EXP2F(g[13])};
            f32x2 eo23 = {EXP2F(g[14]), EXP2F(g[15])};

            // ---- merged dual unitstep, pairwise-batched reciprocals (r19) ----
            f32x2 Ai_a = ei01 + one2, Af_a = ef01 + one2, Ao_a = eo01 + one2;
            f32x2 Ai_b = ei23 + one2, Af_b = ef23 + one2, Ao_b = eo23 + one2;
            f32x2 P_a = VFMA2(Ai_a, qg01, Ai_a);          // Ai*Ag
            f32x2 P_b = VFMA2(Ai_b, qg23, Ai_b);
            f32x2 PAf_a = P_a * Af_a;
            f32x2 PAf_b = P_b * Af_b;
            f32x2 pr = PAf_a * PAf_b;                     // <= 2^92, safe
            f32x2 rr = {RCPF(pr.x), RCPF(pr.y)};
            f32x2 R_a = rr * PAf_b;
            f32x2 R_b = rr * PAf_a;
            f32x2 num_a = VFMA2(c01, P_a, (one2 - qg01) * Af_a);
            f32x2 num_b = VFMA2(c23, P_b, (one2 - qg23) * Af_b);
            c01 = num_a * R_a;                            // = f*c + i*g
            c23 = num_b * R_b;
            f32x2 tq_a = c01 * SCL_TANH;
            f32x2 tq_b = c23 * SCL_TANH;
            f32x2 qc_a = {EXP2F(tq_a.x), EXP2F(tq_a.y)};
            f32x2 qc_b = {EXP2F(tq_b.x), EXP2F(tq_b.y)};
            f32x2 W_a = VFMA2(qc_a, Ao_a, Ao_a);          // (1+qc)*Ao
            f32x2 W_b = VFMA2(qc_b, Ao_b, Ao_b);
            f32x2 pr2 = W_a * W_b;                        // <= 2^69, safe
            f32x2 rr2 = {RCPF(pr2.x), RCPF(pr2.y)};
            f32x2 h01 = ((one2 - qc_a) * W_b) * rr2;      // = tanh(c')*o
            f32x2 h23 = ((one2 - qc_b) * W_a) * rr2;

            // FC partials: float2 fma (compiler packs)
            int t = c * CH + u;
            f32x4 w0 = *(const f32x4*)&s_wfc[t][khalf * 8];       // cls0 u0-3
            f32x4 w1 = *(const f32x4*)&s_wfc[t][khalf * 8 + 4];   // cls1 u0-3
            f32x2 w0a = {w0[0], w0[1]}, w0b = {w0[2], w0[3]};
            f32x2 w1a = {w1[0], w1[1]}, w1b = {w1[2], w1[3]};
            ac0 = VFMA2(w0a, h01, ac0);
            ac0 = VFMA2(w0b, h23, ac0);
            ac1 = VFMA2(w1a, h01, ac1);
            ac1 = VFMA2(w1b, h23, ac1);

            // pack h (single bf16) and publish to the wave's h row
            unsigned p01 = cvt_pk_bf16(h01.x, h01.y);
            unsigned p23 = cvt_pk_bf16(h23.x, h23.y);
            u32x2 wh = {p01, p23};
            *(u32x2*)whH = wh;
        }
        if (c + 1 < NCH) writeC();
    }

    // ---- combine units 0-3 (lane m) and 4-7 (lane m+32), write out ----
    float o0 = ac0.x + ac0.y;
    float o1 = ac1.x + ac1.y;
    o0 += __shfl_xor(o0, 32);
    o1 += __shfl_xor(o1, 32);
    if (!isHi) {
        int gb = blockIdx.x * EPB + wv * EPW + m;
        float2 o;
        o.x = o0 + b_fc[0];
        o.y = o1 + b_fc[1];
        *(float2*)&out[(size_t)gb * 2] = o;
    }
}

extern "C" void kernel_launch(void* const* d_in, const int* in_sizes, int n_in,
                              void* d_out, int out_size, void* d_ws, size_t ws_size,
                              hipStream_t stream) {
    const float* x    = (const float*)d_in[0];
    const float* W_ih = (const float*)d_in[1];
    const float* W_hh = (const float*)d_in[2];
    const float* b_ih = (const float*)d_in[3];
    const float* b_hh = (const float*)d_in[4];
    const float* W_fc = (const float*)d_in[5];
    const float* b_fc = (const float*)d_in[6];
    float* out = (float*)d_out;

    const int B = in_sizes[0] / 240;        // 131072
    dim3 grid(B / EPB), block(THREADS);
    lstm_mfma<<<grid, block, 0, stream>>>(x, W_ih, W_hh, b_ih, b_hh, W_fc, b_fc, out);
}